// Round 4
// baseline (661.030 us; speedup 1.0000x reference)
//
#include <hip/hip_runtime.h>
#include <hip/hip_fp16.h>

// Problem constants
#define N_BATCH 8
#define CI 8
#define CO 16
#define ODIM 66
#define OSP (66*66*66)        // 287496 per (n, co) slab
#define GROUPS 4

// Pass-1 tile constants
#define ROWS 8                 // oh rows per block (9 blocks x 8 = 72 >= 66)
#define SEGS 6                 // ow segments
#define SEGW 11                // ow per thread (6*11 = 66 exact, no ow waste)
#define XW 76                  // LDS x row width (zero-padded halo)
#define XROWS 10               // oh rows + 2 halo
#define XLDS (3*XROWS*XW)      // 2280 floats per ci
#define NTHR 384               // 8 co-pairs x 6 segs x 8 rows = 6 waves
#define NWAVE 6

typedef float f4v __attribute__((ext_vector_type(4)));  // native vector for nontemporal builtins

// ws layout (floats): [0..31] sum, [32..63] sumsq, [64..95] mean, [96..127] rstd
__global__ __launch_bounds__(64) void zero_stats(float* ws) {
    ws[threadIdx.x] = 0.0f;
}

// R2 lesson: 4-co/9-ow mapping demanded ~140 regs under full unroll -> allocator
// split into 48 VGPR + AGPR spill (3x VALU per FMA). This mapping: 2 co x 11 ow
// = 22 acc + 13-float window ~= 70-90 live regs -> pure-VGPR allocation.
__global__ __launch_bounds__(NTHR, 4) void conv_relu_stats(
    const float* __restrict__ x, const float* __restrict__ w,
    float* __restrict__ out, float* __restrict__ stats)
{
    __shared__ float w_lds[216 * 16];     // 13824 B: [ci*27+k][co]
    __shared__ float x_lds[XLDS];         // 9120 B:  [dz][row][iw+2]
    __shared__ float reds[2][NWAVE][4];   // [sum/ss][wave][group]

    const int tid = threadIdx.x;
    const int n   = blockIdx.z;
    const int od  = blockIdx.y;
    const int oh0 = blockIdx.x * ROWS;

    // Stage weights once, with the reference's fp16 round-trip quantization.
    // Layout [idx][co] so a thread's 2 consecutive co are one 8B-aligned float2.
    for (int i = tid; i < 216 * 16; i += NTHR) {
        int idx = i >> 4, co = i & 15;
        int ci = idx / 27, k = idx % 27;
        w_lds[i] = __half2float(__float2half(w[(ci * 16 + co) * 27 + k]));
    }

    const int cp  = tid & 7;        // co pair index: co = 2*cp, 2*cp+1; group = cp>>1
    const int j   = tid >> 3;
    const int seg = j % 6;          // ow segment (width 11)
    const int row = j / 6;          // oh row within tile (0..7)

    float acc[2][SEGW];
    #pragma unroll
    for (int i = 0; i < 2; ++i)
        #pragma unroll
        for (int p = 0; p < SEGW; ++p) acc[i][p] = 0.0f;

    for (int ci = 0; ci < CI; ++ci) {
        __syncthreads();  // protect previous iteration's x_lds reads (and w_lds for ci=0)
        // Stage x tile for this ci: 3 input d-planes x 10 rows x 76 (zero-padded halo)
        for (int i = tid; i < XLDS; i += NTHR) {
            int c    = i % XW;
            int rest = i / XW;
            int r    = rest % XROWS;
            int dz   = rest / XROWS;
            int id = od - 2 + dz;
            int ih = oh0 - 2 + r;
            int iw = c - 2;
            float v = 0.0f;
            if ((unsigned)id < 64u && (unsigned)ih < 64u && (unsigned)iw < 64u)
                v = x[(((size_t)(n * CI + ci) * 64 + id) * 64 + ih) * 64 + iw];
            x_lds[i] = v;
        }
        __syncthreads();

        #pragma unroll
        for (int kd = 0; kd < 3; ++kd) {
            const int dz = 2 - kd;           // id = od - kd
            #pragma unroll
            for (int kh = 0; kh < 3; ++kh) {
                const int rl = row + 2 - kh; // ih = oh - kh
                const float* xp = &x_lds[(dz * XROWS + rl) * XW + seg * SEGW];
                float xw[SEGW + 2];
                #pragma unroll
                for (int c = 0; c < SEGW + 2; ++c) xw[c] = xp[c];
                const int wbase = (((ci * 3 + kd) * 3 + kh) * 3) * 16 + cp * 2;
                #pragma unroll
                for (int kw = 0; kw < 3; ++kw) {
                    const float2 wv = *(const float2*)&w_lds[wbase + kw * 16];
                    #pragma unroll
                    for (int p = 0; p < SEGW; ++p) {
                        const float xv = xw[p + 2 - kw];
                        acc[0][p] = fmaf(wv.x, xv, acc[0][p]);
                        acc[1][p] = fmaf(wv.y, xv, acc[1][p]);
                    }
                }
            }
        }
    }

    // Epilogue: ReLU, store, per-thread stats (only valid rows; ow always valid)
    float s = 0.0f, ss = 0.0f;
    const int oh = oh0 + row;
    const bool ohok = (oh < ODIM);
    #pragma unroll
    for (int i = 0; i < 2; ++i) {
        const int co = cp * 2 + i;
        float* op = &out[(((size_t)(n * CO + co) * ODIM + od) * ODIM + oh) * ODIM + seg * SEGW];
        #pragma unroll
        for (int p = 0; p < SEGW; ++p) {
            if (ohok) {
                const float v = fmaxf(acc[i][p], 0.0f);
                op[p] = v;
                s += v;
                ss = fmaf(v, v, ss);
            }
        }
    }

    // Reduce within wave. Lanes at distance 8,16,32 share the same co-pair;
    // distance 1 merges the two co-pairs of a group.
    s  += __shfl_down(s, 32, 64);  ss += __shfl_down(ss, 32, 64);
    s  += __shfl_down(s, 16, 64);  ss += __shfl_down(ss, 16, 64);
    s  += __shfl_down(s,  8, 64);  ss += __shfl_down(ss,  8, 64);
    s  += __shfl_down(s,  1, 64);  ss += __shfl_down(ss,  1, 64);
    const int wv = tid >> 6, ln = tid & 63;
    if (ln < 8 && (ln & 1) == 0) { reds[0][wv][ln >> 1] = s; reds[1][wv][ln >> 1] = ss; }
    __syncthreads();
    if (tid < 4) {
        float ts = 0.0f, tss = 0.0f;
        #pragma unroll
        for (int v = 0; v < NWAVE; ++v) { ts += reds[0][v][tid]; tss += reds[1][v][tid]; }
        atomicAdd(&stats[n * GROUPS + tid], ts);
        atomicAdd(&stats[32 + n * GROUPS + tid], tss);
    }
}

__global__ __launch_bounds__(64) void finalize_stats(float* ws) {
    const int g = threadIdx.x;
    if (g < 32) {
        const float cnt  = 4.0f * (float)OSP;   // 4 channels per group
        const float mean = ws[g] / cnt;
        const float var  = ws[32 + g] / cnt - mean * mean;
        ws[64 + g] = mean;
        ws[96 + g] = rsqrtf(var + 1e-5f);
    }
}

// In-place normalize: out = (y - mean) * rstd * gamma + beta.
#define NORM_ITER 4
#define NORM_NTHR 256
__global__ __launch_bounds__(NORM_NTHR) void norm_kernel(
    float* __restrict__ out, const float* __restrict__ ws,
    const float* __restrict__ gamma, const float* __restrict__ beta)
{
    const int slab = blockIdx.y;           // n*16 + co
    const int n  = slab >> 4;
    const int co = slab & 15;
    const int gi = n * GROUPS + (co >> 2);
    const float mean = ws[64 + gi];
    const float rstd = ws[96 + gi];
    const float scale = rstd * gamma[co];
    const float shift = beta[co] - mean * scale;

    f4v* p = (f4v*)(out + (size_t)slab * OSP);
    const int base = blockIdx.x * (NORM_NTHR * NORM_ITER) + threadIdx.x;
    #pragma unroll
    for (int it = 0; it < NORM_ITER; ++it) {
        const int idx = base + it * NORM_NTHR;
        if (idx < OSP / 4) {
            f4v v = __builtin_nontemporal_load(&p[idx]);
            v.x = fmaf(v.x, scale, shift);
            v.y = fmaf(v.y, scale, shift);
            v.z = fmaf(v.z, scale, shift);
            v.w = fmaf(v.w, scale, shift);
            __builtin_nontemporal_store(v, &p[idx]);
        }
    }
}

extern "C" void kernel_launch(void* const* d_in, const int* in_sizes, int n_in,
                              void* d_out, int out_size, void* d_ws, size_t ws_size,
                              hipStream_t stream) {
    const float* x     = (const float*)d_in[0];
    const float* w     = (const float*)d_in[1];
    const float* gamma = (const float*)d_in[2];
    const float* beta  = (const float*)d_in[3];
    float* out = (float*)d_out;
    float* ws  = (float*)d_ws;

    zero_stats<<<1, 64, 0, stream>>>(ws);

    dim3 grid1((ODIM + ROWS - 1) / ROWS, ODIM, N_BATCH);   // (9, 66, 8)
    conv_relu_stats<<<grid1, NTHR, 0, stream>>>(x, w, out, ws);

    finalize_stats<<<1, 64, 0, stream>>>(ws);

    const int f4_per_slab = OSP / 4;                       // 71874
    dim3 grid2((f4_per_slab + NORM_NTHR * NORM_ITER - 1) / (NORM_NTHR * NORM_ITER),
               N_BATCH * CO);                              // (71, 128)
    norm_kernel<<<grid2, NORM_NTHR, 0, stream>>>(out, ws, gamma, beta);
}

// Round 5
// 496.142 us; speedup vs baseline: 1.3323x; 1.3323x over previous
//
#include <hip/hip_runtime.h>
#include <hip/hip_fp16.h>

// Problem constants
#define N_BATCH 8
#define CI 8
#define CO 16
#define ODIM 66
#define OSP (66*66*66)        // 287496 per (n, co) slab
#define GROUPS 4

typedef _Float16 half8 __attribute__((ext_vector_type(8)));
typedef float f32x4 __attribute__((ext_vector_type(4)));
typedef float f4v  __attribute__((ext_vector_type(4)));

// MFMA conv tiling: block = (n, od, 8 oh-rows). 8*66 = 528 positions = 33 tiles
// of 16. 3 waves x 11 tiles. K = 28 taps x 8 ci = 7 chunks of 32.
#define OHT 8
#define NWAVES 3
#define TPW 11
#define NTHR 192
#define XIH 10                 // staged ih rows (8 + 2 halo)
#define XIW 68                 // staged iw (64 + 2+2 zero halo)
#define XSZ (3*XIH*XIW*8)      // 16320 halfs
#define WSZ (28*16*8)          // 3584 halfs, tap 27 = zero pad

// ws layout (floats): [0..31] sum, [32..63] sumsq, [64..95] mean, [96..127] rstd
__global__ __launch_bounds__(64) void zero_stats(float* ws) {
    ws[threadIdx.x] = 0.0f;
}

__global__ __launch_bounds__(NTHR, 3) void conv_mfma(
    const float* __restrict__ x, const float* __restrict__ w,
    float* __restrict__ out, float* __restrict__ stats)
{
    __shared__ _Float16 XT[XSZ];          // [dz][ih_l][iw_p][ci]
    __shared__ _Float16 WT[WSZ];          // [t][co][ci]
    __shared__ float reds[2][NWAVES][GROUPS];

    const int tid = threadIdx.x;
    const int n   = blockIdx.z;
    const int od  = blockIdx.y;
    const int oh0 = blockIdx.x * OHT;

    // Stage weights (fp16 round-trip per reference). WT[t][co][ci], t=27 zeros.
    for (int i = tid; i < WSZ; i += NTHR) {
        int t  = i >> 7;          // /128
        int co = (i >> 3) & 15;
        int ci = i & 7;
        float v = (t < 27) ? w[(ci * 16 + co) * 27 + t] : 0.0f;
        WT[i] = (_Float16)v;
    }
    // Stage x interior: consecutive tid -> consecutive iw (coalesced).
    for (int j = tid; j < 3 * XIH * 8 * 64; j += NTHR) {
        int iw   = j & 63;
        int ci   = (j >> 6) & 7;
        int t2   = j >> 9;
        int ih_l = t2 % 10;
        int dz   = t2 / 10;
        int id = od - 2 + dz;
        int ih = oh0 - 2 + ih_l;
        float v = 0.0f;
        if ((unsigned)id < 64u && (unsigned)ih < 64u)
            v = x[(((size_t)(n * CI + ci) * 64 + id) * 64 + ih) * 64 + iw];
        XT[((dz * XIH + ih_l) * XIW + (iw + 2)) * 8 + ci] = (_Float16)v;
    }
    // Zero halo columns iw_p in {0,1,66,67}
    for (int i = tid; i < 3 * XIH * 4 * 8; i += NTHR) {
        int ci   = i & 7;
        int col  = (i >> 3) & 3;
        int t2   = i >> 5;
        int ih_l = t2 % 10;
        int dz   = t2 / 10;
        int iwp  = (col < 2) ? col : (64 + col);
        XT[((dz * XIH + ih_l) * XIW + iwp) * 8 + ci] = (_Float16)0.0f;
    }
    __syncthreads();

    const int lane = tid & 63;
    const int wv   = tid >> 6;
    const int q    = lane >> 4;     // quad: tap-within-chunk (A/B k), row-block (D)
    const int col  = lane & 15;     // co (B/D), position m (A)

    // B fragments: lane needs WT[t= c*4+q][co=col][ci=0..7] -> one b128 each
    half8 bfrag[7];
    #pragma unroll
    for (int c = 0; c < 7; ++c) {
        int t = c * 4 + q;
        bfrag[c] = *(const half8*)&WT[(t * 16 + col) * 8];
    }
    // A-gather address deltas per chunk (in halfs). t=27 clamps to 26 (B=0).
    int dt[7];
    #pragma unroll
    for (int c = 0; c < 7; ++c) {
        int t = c * 4 + q; if (t > 26) t = 26;
        int kd = t / 9, r = t - kd * 9, kh = r / 3, kw = r - kh * 3;
        dt[c] = (kd * (XIH * XIW) + kh * XIW + kw) * 8;
    }
    // Base addresses per tile: position p = (wv*11+i)*16 + col in 8x66 grid
    int baseh[TPW];
    #pragma unroll
    for (int i = 0; i < TPW; ++i) {
        int p   = (wv * TPW + i) * 16 + col;
        int ohl = p / 66, ow = p - ohl * 66;
        baseh[i] = ((2 * XIH + ohl + 2) * XIW + (ow + 2)) * 8;
    }

    f32x4 acc[TPW];
    #pragma unroll
    for (int i = 0; i < TPW; ++i) acc[i] = (f32x4){0.f, 0.f, 0.f, 0.f};

    // Main loop: 77 (ds_read_b128 + MFMA), no barriers. c outer keeps the
    // 11 inner MFMAs independent (different acc).
    #pragma unroll
    for (int c = 0; c < 7; ++c) {
        #pragma unroll
        for (int i = 0; i < TPW; ++i) {
            half8 a = *(const half8*)&XT[baseh[i] - dt[c]];
            acc[i] = __builtin_amdgcn_mfma_f32_16x16x32_f16(a, bfrag[c], acc[i], 0, 0, 0);
        }
    }

    // Epilogue: D lane holds rows q*4+r, col co. ReLU + store + stats.
    // Rows with oh >= 66 have all-zero staged x -> acc==0 -> skip store.
    float s = 0.0f, ss = 0.0f;
    const int co = col;
    float* slab = out + (size_t)(n * CO + co) * OSP + (size_t)od * 4356 + oh0 * 66;
    #pragma unroll
    for (int i = 0; i < TPW; ++i) {
        #pragma unroll
        for (int r = 0; r < 4; ++r) {
            int p   = (wv * TPW + i) * 16 + q * 4 + r;
            int ohl = p / 66, ow = p - ohl * 66;
            if (oh0 + ohl < ODIM) {
                float v = fmaxf(acc[i][r], 0.0f);
                slab[ohl * 66 + ow] = v;
                s += v;
                ss = fmaf(v, v, ss);
            }
        }
    }

    // Reduce: xor16/32 merges lanes with same co; xor1/2 merges the 4 co of a group.
    s += __shfl_xor(s, 16, 64);  ss += __shfl_xor(ss, 16, 64);
    s += __shfl_xor(s, 32, 64);  ss += __shfl_xor(ss, 32, 64);
    s += __shfl_xor(s, 1, 64);   ss += __shfl_xor(ss, 1, 64);
    s += __shfl_xor(s, 2, 64);   ss += __shfl_xor(ss, 2, 64);
    if (lane < 16 && (lane & 3) == 0) {
        reds[0][wv][lane >> 2] = s;
        reds[1][wv][lane >> 2] = ss;
    }
    __syncthreads();
    if (tid < GROUPS) {
        float ts = 0.0f, tss = 0.0f;
        #pragma unroll
        for (int v = 0; v < NWAVES; ++v) { ts += reds[0][v][tid]; tss += reds[1][v][tid]; }
        atomicAdd(&stats[n * GROUPS + tid], ts);
        atomicAdd(&stats[32 + n * GROUPS + tid], tss);
    }
}

__global__ __launch_bounds__(64) void finalize_stats(float* ws) {
    const int g = threadIdx.x;
    if (g < 32) {
        const float cnt  = 4.0f * (float)OSP;   // 4 channels per group
        const float mean = ws[g] / cnt;
        const float var  = ws[32 + g] / cnt - mean * mean;
        ws[64 + g] = mean;
        ws[96 + g] = rsqrtf(var + 1e-5f);
    }
}

// In-place normalize: out = (y - mean) * rstd * gamma + beta.
#define NORM_ITER 4
#define NORM_NTHR 256
__global__ __launch_bounds__(NORM_NTHR) void norm_kernel(
    float* __restrict__ out, const float* __restrict__ ws,
    const float* __restrict__ gamma, const float* __restrict__ beta)
{
    const int slab = blockIdx.y;           // n*16 + co
    const int n  = slab >> 4;
    const int co = slab & 15;
    const int gi = n * GROUPS + (co >> 2);
    const float mean = ws[64 + gi];
    const float rstd = ws[96 + gi];
    const float scale = rstd * gamma[co];
    const float shift = beta[co] - mean * scale;

    f4v* p = (f4v*)(out + (size_t)slab * OSP);
    const int base = blockIdx.x * (NORM_NTHR * NORM_ITER) + threadIdx.x;
    #pragma unroll
    for (int it = 0; it < NORM_ITER; ++it) {
        const int idx = base + it * NORM_NTHR;
        if (idx < OSP / 4) {
            f4v v = __builtin_nontemporal_load(&p[idx]);
            v.x = fmaf(v.x, scale, shift);
            v.y = fmaf(v.y, scale, shift);
            v.z = fmaf(v.z, scale, shift);
            v.w = fmaf(v.w, scale, shift);
            __builtin_nontemporal_store(v, &p[idx]);
        }
    }
}

extern "C" void kernel_launch(void* const* d_in, const int* in_sizes, int n_in,
                              void* d_out, int out_size, void* d_ws, size_t ws_size,
                              hipStream_t stream) {
    const float* x     = (const float*)d_in[0];
    const float* w     = (const float*)d_in[1];
    const float* gamma = (const float*)d_in[2];
    const float* beta  = (const float*)d_in[3];
    float* out = (float*)d_out;
    float* ws  = (float*)d_ws;

    zero_stats<<<1, 64, 0, stream>>>(ws);

    dim3 grid1((ODIM + OHT - 1) / OHT, ODIM, N_BATCH);     // (9, 66, 8)
    conv_mfma<<<grid1, NTHR, 0, stream>>>(x, w, out, ws);

    finalize_stats<<<1, 64, 0, stream>>>(ws);

    const int f4_per_slab = OSP / 4;                       // 71874
    dim3 grid2((f4_per_slab + NORM_NTHR * NORM_ITER - 1) / (NORM_NTHR * NORM_ITER),
               N_BATCH * CO);                              // (71, 128)
    norm_kernel<<<grid2, NORM_NTHR, 0, stream>>>(out, ws, gamma, beta);
}

// Round 6
// 363.969 us; speedup vs baseline: 1.8162x; 1.3631x over previous
//
#include <hip/hip_runtime.h>
#include <hip/hip_fp16.h>

// Problem constants
#define N_BATCH 8
#define CI 8
#define CO 16
#define ODIM 66
#define OSP (66*66*66)        // 287496 per (n, co) slab
#define GROUPS 4

typedef _Float16 half8 __attribute__((ext_vector_type(8)));
typedef float f32x4 __attribute__((ext_vector_type(4)));

// MFMA conv tiling: block = (n, od, 8 oh-rows). 8*66 = 528 positions = 33 tiles
// of 16. 3 waves x 11 tiles. K = 28 taps x 8 ci = 7 chunks of 32.
#define OHT 8
#define NWAVES 3
#define TPW 11
#define NTHR 192
#define XIH 10                 // staged ih rows (8 + 2 halo)
#define XIW 68                 // staged iw (64 + 2+2 zero halo)
#define XPOS (3*XIH*XIW)       // 2040 staged positions
#define XSZ (XPOS*8)           // 16320 halfs
#define WSZ (28*16*8)          // 3584 halfs, tap 27 = zero pad
#define XPLANE 262144          // 64*64*64 floats per (n,ci) plane

// ws layout (floats): [0..31] sum, [32..63] sumsq
__global__ __launch_bounds__(64) void zero_stats(float* ws) {
    ws[threadIdx.x] = 0.0f;
}

__global__ __launch_bounds__(NTHR, 3) void conv_mfma(
    const float* __restrict__ x, const float* __restrict__ w,
    float* __restrict__ out, float* __restrict__ stats)
{
    __shared__ _Float16 XT[XSZ];          // [dz][ih_l][iw_p][ci]
    __shared__ _Float16 WT[WSZ];          // [t][co][ci]
    __shared__ float reds[2][NWAVES][GROUPS];

    const int tid = threadIdx.x;
    const int n   = blockIdx.z;
    const int od  = blockIdx.y;
    const int oh0 = blockIdx.x * OHT;

    // Stage weights (fp16 round-trip per reference). WT[t][co][ci], t=27 zeros.
    // Thread owns one (t,co): 8 strided scalar loads -> one conflict-free b128.
    for (int i = tid; i < 28 * 16; i += NTHR) {
        int t = i >> 4, co = i & 15;
        half8 h;
        #pragma unroll
        for (int ci = 0; ci < 8; ++ci) {
            float v = (t < 27) ? w[(ci * 16 + co) * 27 + t] : 0.0f;
            h[ci] = (_Float16)v;
        }
        *(half8*)&WT[i * 8] = h;
    }

    // Stage x: thread owns one position (dz, ih_l, iw_p), gathers 8 ci.
    // Each of the 8 loads is wave-coalesced (consecutive lanes = consecutive iw);
    // the half8 write is 16B/lane contiguous -> conflict-free ds_write_b128.
    // Halo (id/ih/iw out of range) folds into the same predicate.
    const size_t nbase = (size_t)(n * CI) * XPLANE;
    for (int p = tid; p < XPOS; p += NTHR) {
        int dz   = p / (XIH * XIW);
        int rem  = p - dz * (XIH * XIW);
        int ih_l = rem / XIW;
        int iw   = (rem - ih_l * XIW) - 2;
        int id = od - 2 + dz;
        int ih = oh0 - 2 + ih_l;
        bool ok = ((unsigned)id < 64u) & ((unsigned)ih < 64u) & ((unsigned)iw < 64u);
        size_t base = nbase + (ok ? ((size_t)id * 4096 + ih * 64 + iw) : 0);
        half8 h;
        #pragma unroll
        for (int ci = 0; ci < 8; ++ci) {
            float v = x[base + (size_t)ci * XPLANE];   // unconditional, safe (clamped in-plane-set)
            h[ci] = ok ? (_Float16)v : (_Float16)0.0f;
        }
        *(half8*)&XT[p * 8] = h;
    }
    __syncthreads();

    const int lane = tid & 63;
    const int wv   = tid >> 6;
    const int q    = lane >> 4;     // quad: tap-within-chunk (A/B k), row-block (D)
    const int col  = lane & 15;     // co (B/D), position m (A)

    // B fragments: lane needs WT[t= c*4+q][co=col][ci=0..7] -> one b128 each
    half8 bfrag[7];
    #pragma unroll
    for (int c = 0; c < 7; ++c) {
        int t = c * 4 + q;
        bfrag[c] = *(const half8*)&WT[(t * 16 + col) * 8];
    }
    // A-gather address deltas per chunk (in halfs). t=27 clamps to 26 (B=0).
    int dt[7];
    #pragma unroll
    for (int c = 0; c < 7; ++c) {
        int t = c * 4 + q; if (t > 26) t = 26;
        int kd = t / 9, r = t - kd * 9, kh = r / 3, kw = r - kh * 3;
        dt[c] = (kd * (XIH * XIW) + kh * XIW + kw) * 8;
    }
    // Base addresses per tile: position p = (wv*11+i)*16 + col in 8x66 grid
    int baseh[TPW];
    #pragma unroll
    for (int i = 0; i < TPW; ++i) {
        int p   = (wv * TPW + i) * 16 + col;
        int ohl = p / 66, ow = p - ohl * 66;
        baseh[i] = ((2 * XIH + ohl + 2) * XIW + (ow + 2)) * 8;
    }

    f32x4 acc[TPW];
    #pragma unroll
    for (int i = 0; i < TPW; ++i) acc[i] = (f32x4){0.f, 0.f, 0.f, 0.f};

    // Main loop: 77 (ds_read_b128 + MFMA), no barriers. c outer keeps the
    // 11 inner MFMAs independent (different acc).
    #pragma unroll
    for (int c = 0; c < 7; ++c) {
        #pragma unroll
        for (int i = 0; i < TPW; ++i) {
            half8 a = *(const half8*)&XT[baseh[i] - dt[c]];
            acc[i] = __builtin_amdgcn_mfma_f32_16x16x32_f16(a, bfrag[c], acc[i], 0, 0, 0);
        }
    }

    // Epilogue: D lane holds rows q*4+r, col co. ReLU + store + stats.
    float s = 0.0f, ss = 0.0f;
    const int co = col;
    float* slab = out + (size_t)(n * CO + co) * OSP + (size_t)od * 4356 + oh0 * 66;
    #pragma unroll
    for (int i = 0; i < TPW; ++i) {
        #pragma unroll
        for (int r = 0; r < 4; ++r) {
            int p   = (wv * TPW + i) * 16 + q * 4 + r;
            int ohl = p / 66, ow = p - ohl * 66;
            if (oh0 + ohl < ODIM) {
                float v = fmaxf(acc[i][r], 0.0f);
                slab[ohl * 66 + ow] = v;
                s += v;
                ss = fmaf(v, v, ss);
            }
        }
    }

    // Reduce: xor16/32 merges lanes with same co; xor1/2 merges the 4 co of a group.
    s += __shfl_xor(s, 16, 64);  ss += __shfl_xor(ss, 16, 64);
    s += __shfl_xor(s, 32, 64);  ss += __shfl_xor(ss, 32, 64);
    s += __shfl_xor(s, 1, 64);   ss += __shfl_xor(ss, 1, 64);
    s += __shfl_xor(s, 2, 64);   ss += __shfl_xor(ss, 2, 64);
    if (lane < 16 && (lane & 3) == 0) {
        reds[0][wv][lane >> 2] = s;
        reds[1][wv][lane >> 2] = ss;
    }
    __syncthreads();
    if (tid < GROUPS) {
        float ts = 0.0f, tss = 0.0f;
        #pragma unroll
        for (int v = 0; v < NWAVES; ++v) { ts += reds[0][v][tid]; tss += reds[1][v][tid]; }
        atomicAdd(&stats[n * GROUPS + tid], ts);
        atomicAdd(&stats[32 + n * GROUPS + tid], tss);
    }
}

// In-place normalize: out = (y - mean) * rstd * gamma + beta.
// finalize folded in: each block derives mean/rstd from the raw sums (cheap).
#define NORM_ITER 4
#define NORM_NTHR 256
__global__ __launch_bounds__(NORM_NTHR) void norm_kernel(
    float* __restrict__ out, const float* __restrict__ ws,
    const float* __restrict__ gamma, const float* __restrict__ beta)
{
    const int slab = blockIdx.y;           // n*16 + co
    const int n  = slab >> 4;
    const int co = slab & 15;
    const int gi = n * GROUPS + (co >> 2);
    const float cnt  = 4.0f * (float)OSP;
    const float mean = ws[gi] / cnt;
    const float var  = ws[32 + gi] / cnt - mean * mean;
    const float rstd = rsqrtf(var + 1e-5f);
    const float scale = rstd * gamma[co];
    const float shift = beta[co] - mean * scale;

    float4* p = (float4*)(out + (size_t)slab * OSP);
    const int base = blockIdx.x * (NORM_NTHR * NORM_ITER) + threadIdx.x;
    #pragma unroll
    for (int it = 0; it < NORM_ITER; ++it) {
        const int idx = base + it * NORM_NTHR;
        if (idx < OSP / 4) {
            float4 v = p[idx];
            v.x = fmaf(v.x, scale, shift);
            v.y = fmaf(v.y, scale, shift);
            v.z = fmaf(v.z, scale, shift);
            v.w = fmaf(v.w, scale, shift);
            p[idx] = v;
        }
    }
}

extern "C" void kernel_launch(void* const* d_in, const int* in_sizes, int n_in,
                              void* d_out, int out_size, void* d_ws, size_t ws_size,
                              hipStream_t stream) {
    const float* x     = (const float*)d_in[0];
    const float* w     = (const float*)d_in[1];
    const float* gamma = (const float*)d_in[2];
    const float* beta  = (const float*)d_in[3];
    float* out = (float*)d_out;
    float* ws  = (float*)d_ws;

    zero_stats<<<1, 64, 0, stream>>>(ws);

    dim3 grid1((ODIM + OHT - 1) / OHT, ODIM, N_BATCH);     // (9, 66, 8)
    conv_mfma<<<grid1, NTHR, 0, stream>>>(x, w, out, ws);

    const int f4_per_slab = OSP / 4;                       // 71874
    dim3 grid2((f4_per_slab + NORM_NTHR * NORM_ITER - 1) / (NORM_NTHR * NORM_ITER),
               N_BATCH * CO);                              // (71, 128)
    norm_kernel<<<grid2, NORM_NTHR, 0, stream>>>(out, ws, gamma, beta);
}